// Round 9
// baseline (452.644 us; speedup 1.0000x reference)
//
#include <hip/hip_runtime.h>
#include <hip/hip_cooperative_groups.h>

namespace cg = cooperative_groups;

#define T_SEQ 2048
#define MDL   1024
#define NH    8
#define HD    128
#define SPLIT 4

typedef __bf16 bf16;
typedef __bf16 bf16x8 __attribute__((ext_vector_type(8)));
typedef __bf16 bf16x4 __attribute__((ext_vector_type(4)));
typedef float  f32x4  __attribute__((ext_vector_type(4)));

#define GLB(p) ((const __attribute__((address_space(1))) void*)(p))
#define LDS(p) ((__attribute__((address_space(3))) void*)(p))

#if __has_builtin(__builtin_amdgcn_exp2f)
#define EXP2(x) __builtin_amdgcn_exp2f(x)
#else
#define EXP2(x) __expf((x) * 0.6931471805599453f)
#endif

// Q is pre-scaled by 2^-7 * log2(e) so attention P = exp2(QK) directly.
#define QSCALE 0.011271055f

// K image per (bh, jt<32): [d>>3][t&63][d&7]          (8192 elems)
// V image per (bh, jt<32): [p>>3][d][p&7], p = 4*(t&15) + (t>>4)  (j-permuted)

// ===========================================================================
// Phase bodies (shared between the cooperative mega-kernel and the 5-kernel
// fallback). All LDS passed as a pointer into one 64 KB block.
// ===========================================================================

// ---- prep: vb<2048: x fp32->bf16; vb>=2048: weight transpose to B^T ----
__device__ __forceinline__ void prep_body(
    int vb, int tid, bf16* t_lds,
    const float* x, const float* wq, const float* wk, const float* wv,
    const float* wo, bf16* xb, bf16* Wt, bf16* Wot)
{
    if (vb < 2048) {
        size_t i = ((size_t)vb * 256 + tid) * 8;
        float4 v0 = *(const float4*)(x + i);
        float4 v1 = *(const float4*)(x + i + 4);
        bf16x8 o;
        o[0]=(bf16)v0.x; o[1]=(bf16)v0.y; o[2]=(bf16)v0.z; o[3]=(bf16)v0.w;
        o[4]=(bf16)v1.x; o[5]=(bf16)v1.y; o[6]=(bf16)v1.z; o[7]=(bf16)v1.w;
        *(bf16x8*)(xb + i) = o;
        return;
    }
    const int bx = vb - 2048;
    const int sec = bx >> 8;
    const int tile = bx & 255;
    const int k0 = (tile >> 4) * 64, n0 = (tile & 15) * 64;
    const float* src = sec == 0 ? wq : sec == 1 ? wk : sec == 2 ? wv : wo;
    bf16* dst = sec < 3 ? (Wt + (size_t)sec * MDL * MDL) : Wot;

    const int ir = tid >> 2, jc = (tid & 3) * 16;
    const float* sp = src + (size_t)(k0 + ir) * MDL + n0 + jc;
    __syncthreads();                    // t_lds WAR guard across vb iterations
    #pragma unroll
    for (int c = 0; c < 4; ++c) {
        float4 v = *(const float4*)(sp + c * 4);
        bf16x4 o; o[0]=(bf16)v.x; o[1]=(bf16)v.y; o[2]=(bf16)v.z; o[3]=(bf16)v.w;
        *(bf16x4*)&t_lds[ir * 72 + jc + c * 4] = o;
    }
    __syncthreads();
    bf16x8 o0, o1;
    #pragma unroll
    for (int jj = 0; jj < 8; ++jj) {
        o0[jj] = t_lds[(jc + jj) * 72 + ir];
        o1[jj] = t_lds[(jc + 8 + jj) * 72 + ir];
    }
    bf16* dp = dst + (size_t)(n0 + ir) * MDL + k0 + jc;
    *(bf16x8*)dp = o0;
    *(bf16x8*)(dp + 8) = o1;
}

// ---- qkv GEMM + RoPE: BK=64, swizzled reads (r7), single-barrier
// double-buffered pipeline (r8). smem = 64 KB: a[2][8192] | b[2][8192]. ----
__device__ __forceinline__ void qkv_body(
    int bx, int tid, bf16* smem,
    const bf16* xb, const bf16* Wt,
    bf16* Qb, bf16* Kt, bf16* Vt)
{
    bf16* a_lds = smem;
    bf16* b_lds = smem + 16384;

    const int nt = bx % 24, mt = bx / 24;
    const int n0 = nt * 128, m0 = mt * 128;
    const int section = n0 >> 10;
    const int h = (n0 & 1023) >> 7;

    const int lane = tid & 63, w = tid >> 6;
    const int quad = lane >> 4, l15 = lane & 15;
    const int wr = w >> 1, wc = w & 1;
    const int srow = lane >> 3;

    const int csw = ((lane & 7) ^ srow) * 8;   // inverse-swizzled source col
    const bf16* gA = xb + (size_t)m0 * MDL + csw;
    const bf16* gB = Wt + (size_t)n0 * MDL + csw;

    f32x4 acc[4][4] = {};

    auto stage = [&](int k0, int buf) {
        #pragma unroll
        for (int i = 0; i < 4; ++i) {
            const int ch = w * 4 + i;
            const int row = ch * 8 + srow;
            __builtin_amdgcn_global_load_lds(GLB(gA + (size_t)row * MDL + k0),
                                             LDS(&a_lds[buf * 8192 + ch * 512]), 16, 0, 0);
            __builtin_amdgcn_global_load_lds(GLB(gB + (size_t)row * MDL + k0),
                                             LDS(&b_lds[buf * 8192 + ch * 512]), 16, 0, 0);
        }
    };

    auto compute = [&](int buf) {
        #pragma unroll
        for (int hh = 0; hh < 2; ++hh) {
            bf16x8 af[4], bfr[4];
            #pragma unroll
            for (int mi = 0; mi < 4; ++mi) {
                const int ra = wr * 64 + mi * 16 + l15;
                af[mi] = *(const bf16x8*)&a_lds[buf * 8192 + ra * 64 + ((hh * 4 + quad) ^ (ra & 7)) * 8];
            }
            #pragma unroll
            for (int ni = 0; ni < 4; ++ni) {
                const int rb = wc * 64 + ni * 16 + l15;
                bfr[ni] = *(const bf16x8*)&b_lds[buf * 8192 + rb * 64 + ((hh * 4 + quad) ^ (rb & 7)) * 8];
            }
            #pragma unroll
            for (int mi = 0; mi < 4; ++mi)
                #pragma unroll
                for (int ni = 0; ni < 4; ++ni)
                    acc[mi][ni] = __builtin_amdgcn_mfma_f32_16x16x32_bf16(af[mi], bfr[ni], acc[mi][ni], 0, 0, 0);
        }
    };

    __syncthreads();                       // smem reuse guard (prev vb/phase)
    stage(0, 0);
    __syncthreads();                       // buf0 ready

    #pragma unroll 1
    for (int k0 = 0; k0 < MDL; k0 += 128) {
        stage(k0 + 64, 1);                 // prefetch flies under compute(0)
        compute(0);
        __syncthreads();                   // drains prefetch; buf1 ready
        if (k0 + 128 < MDL) stage(k0 + 128, 0);
        compute(1);
        __syncthreads();
    }

    const int bdx = m0 >> 11;
    const int t0 = m0 & (T_SEQ - 1);
    const int bh = bdx * NH + h;

    if (section == 2) {
        // ---- V -> j-permuted image via LDS, linear coalesced out ----
        #pragma unroll
        for (int c = 0; c < 2; ++c) {
            if (wc == c) {
                #pragma unroll
                for (int mi = 0; mi < 4; ++mi)
                    #pragma unroll
                    for (int r = 0; r < 4; ++r) {
                        int p = 16 * quad + 4 * r + mi;       // permuted pos
                        int base = (wr * 8 + (p >> 3)) * 512 + (p & 7);
                        #pragma unroll
                        for (int ni = 0; ni < 4; ++ni)
                            smem[base + (ni * 16 + l15) * 8] = (bf16)acc[mi][ni][r];
                    }
            }
            __syncthreads();
            {
                const int t8 = tid >> 4;
                bf16* vp = Vt + ((size_t)(bh * 32 + (t0 >> 6) + (t8 >> 3))) * 8192
                              + (t8 & 7) * 1024 + c * 512 + (tid & 15) * 32;
                #pragma unroll
                for (int k = 0; k < 4; ++k)
                    *(bf16x8*)(vp + k * 8) = *(const bf16x8*)&smem[tid * 32 + k * 8];
            }
            __syncthreads();
        }
        return;
    }

    float fr_n[2];
    #pragma unroll
    for (int ni = 0; ni < 2; ++ni)
        fr_n[ni] = __expf(-(float)(ni * 16 + l15) * 0.28782313662425573f);

    if (section == 0) {
        // ---- Q: [bh][t][d], RoPE on d<64, all scaled by QSCALE ----
        #pragma unroll
        for (int mi = 0; mi < 4; ++mi) {
            #pragma unroll
            for (int r = 0; r < 4; ++r) {
                int t = t0 + wr * 64 + mi * 16 + quad * 4 + r;
                bf16* orow = Qb + ((size_t)bh * T_SEQ + t) * HD;
                if (wc == 0) {
                    #pragma unroll
                    for (int ni = 0; ni < 2; ++ni) {
                        int d = ni * 16 + l15;
                        float ang = (float)t * fr_n[ni];
                        float sn = __sinf(ang), cs = __cosf(ang);
                        float ev = acc[mi][ni][r];
                        float ov = acc[mi][ni + 2][r];
                        orow[d]      = (bf16)((ev * cs - ov * sn) * QSCALE);
                        orow[d + 32] = (bf16)((ev * sn + ov * cs) * QSCALE);
                    }
                } else {
                    #pragma unroll
                    for (int ni = 0; ni < 4; ++ni)
                        orow[64 + ni * 16 + l15] = (bf16)(acc[mi][ni][r] * QSCALE);
                }
            }
        }
    } else {
        // ---- K -> image via LDS (half = one 64-t jt tile), RoPE fused ----
        #pragma unroll
        for (int c = 0; c < 2; ++c) {
            if (wr == c) {
                #pragma unroll
                for (int mi = 0; mi < 4; ++mi) {
                    #pragma unroll
                    for (int r = 0; r < 4; ++r) {
                        int tl = mi * 16 + quad * 4 + r;
                        int t = t0 + c * 64 + tl;
                        if (wc == 0) {
                            #pragma unroll
                            for (int ni = 0; ni < 2; ++ni) {
                                int d = ni * 16 + l15;
                                float ang = (float)t * fr_n[ni];
                                float sn = __sinf(ang), cs = __cosf(ang);
                                float ev = acc[mi][ni][r];
                                float ov = acc[mi][ni + 2][r];
                                smem[(d >> 3) * 512 + tl * 8 + (d & 7)] = (bf16)(ev * cs - ov * sn);
                                int d2 = d + 32;
                                smem[(d2 >> 3) * 512 + tl * 8 + (d2 & 7)] = (bf16)(ev * sn + ov * cs);
                            }
                        } else {
                            #pragma unroll
                            for (int ni = 0; ni < 4; ++ni) {
                                int d = 64 + ni * 16 + l15;
                                smem[(d >> 3) * 512 + tl * 8 + (d & 7)] = (bf16)acc[mi][ni][r];
                            }
                        }
                    }
                }
            }
            __syncthreads();
            {
                bf16* kp = Kt + ((size_t)(bh * 32 + (t0 >> 6) + c)) * 8192 + tid * 32;
                #pragma unroll
                for (int k = 0; k < 4; ++k)
                    *(bf16x8*)(kp + k * 8) = *(const bf16x8*)&smem[tid * 32 + k * 8];
            }
            __syncthreads();
        }
    }
}

// ---- attn: r3 config (measured best): reg-prefetch 1-deep, SP=4, XCD
// remap (2 heads/XCD = 4MB L2-resident KV). smem: k[8192]|v[8192]|p[9216].
__device__ __forceinline__ void attn_body(
    int bx, int tid, bf16* smem,
    const bf16* Qb, const bf16* Kt, const bf16* Vt,
    bf16* PO, float* Pl)
{
    bf16* k_lds = smem;
    bf16* v_lds = smem + 8192;
    const int lane = tid & 63, w = tid >> 6;
    bf16* p_w = smem + 16384 + w * (32 * 72);

    const int quad = lane >> 4, l15 = lane & 15;
    const int xcd  = bx & 7;
    const int slot = bx >> 3;
    const int bh   = xcd * 2 + (slot >> 5);
    const int s0   = slot & (SPLIT - 1);
    const int ip   = (slot >> 2) & 7;
    const int tA = 2 * ip + 2;

    const bf16* Kbh = Kt + (size_t)bh * 32 * 8192;
    const bf16* Vbh = Vt + (size_t)bh * 32 * 8192;

    bf16x8 kreg[4], vreg[4];
    bf16x8 qf[2][4];
    f32x4 Of[2][8];
    float l_r[2][4];

    auto fetch = [&](int g) {
        const int jt = (g < tA) ? g : g - tA;
        const bf16* kt = Kbh + (size_t)jt * 8192 + tid * 8;
        const bf16* vt = Vbh + (size_t)jt * 8192 + tid * 8;
        #pragma unroll
        for (int k = 0; k < 4; ++k) {
            kreg[k] = *(const bf16x8*)(kt + k * 2048);
            vreg[k] = *(const bf16x8*)(vt + k * 2048);
        }
    };

    fetch(s0);
    int pqt = -1;

    #pragma unroll 1
    for (int g = s0; g < 34; g += SPLIT) {
        const int ph = (g >= tA);
        const int qt = ph ? 15 - ip : ip;
        const int jt = ph ? g - tA : g;

        if (qt != pqt) {
            if (pqt >= 0) {
                const size_t slotq = ((size_t)bh * 16 + pqt) * SPLIT + s0;
                #pragma unroll
                for (int mi = 0; mi < 2; ++mi)
                    #pragma unroll
                    for (int r = 0; r < 4; ++r) {
                        float ls = l_r[mi][r];
                        ls += __shfl_xor(ls, 1); ls += __shfl_xor(ls, 2);
                        ls += __shfl_xor(ls, 4); ls += __shfl_xor(ls, 8);
                        const int row = w * 32 + mi * 16 + quad * 4 + r;
                        if (l15 == 0) Pl[slotq * 128 + row] = ls;
                        bf16* pr = PO + (slotq * 128 + row) * 128;
                        #pragma unroll
                        for (int di = 0; di < 8; ++di)
                            pr[di * 16 + l15] = (bf16)Of[mi][di][r];
                    }
            }
            #pragma unroll
            for (int mi = 0; mi < 2; ++mi) {
                const bf16* qrow = Qb + ((size_t)bh * T_SEQ + qt * 128 + w * 32 + mi * 16 + l15) * HD + quad * 8;
                #pragma unroll
                for (int kk = 0; kk < 4; ++kk)
                    qf[mi][kk] = *(const bf16x8*)(qrow + kk * 32);
                #pragma unroll
                for (int di = 0; di < 8; ++di) Of[mi][di] = (f32x4){0.f, 0.f, 0.f, 0.f};
                #pragma unroll
                for (int r = 0; r < 4; ++r) l_r[mi][r] = 0.f;
            }
            pqt = qt;
        }

        __syncthreads();                       // all waves done reading prev tile
        #pragma unroll
        for (int k = 0; k < 4; ++k) {          // regs -> LDS (waits vmcnt of fetch)
            *(bf16x8*)&k_lds[k * 2048 + tid * 8] = kreg[k];
            *(bf16x8*)&v_lds[k * 2048 + tid * 8] = vreg[k];
        }
        if (g + SPLIT < 34) fetch(g + SPLIT);  // next tile flies under compute
        __syncthreads();                       // tiles visible

        // ---- S = Q K^T ----
        f32x4 sa[2][4] = {};
        #pragma unroll
        for (int kk = 0; kk < 4; ++kk) {
            bf16x8 kb[4];
            #pragma unroll
            for (int ni = 0; ni < 4; ++ni)
                kb[ni] = *(const bf16x8*)&k_lds[(kk * 4 + quad) * 512 + (ni * 16 + l15) * 8];
            #pragma unroll
            for (int ni = 0; ni < 4; ++ni)
                #pragma unroll
                for (int mi = 0; mi < 2; ++mi)
                    sa[mi][ni] = __builtin_amdgcn_mfma_f32_16x16x32_bf16(qf[mi][kk], kb[ni], sa[mi][ni], 0, 0, 0);
        }

        // ---- P = exp2(S), mask on diagonal tiles ----
        const bool diag = (jt >= 2 * qt);
        #pragma unroll
        for (int mi = 0; mi < 2; ++mi) {
            const int rowb = w * 32 + mi * 16 + quad * 4;
            #pragma unroll
            for (int r = 0; r < 4; ++r) {
                float ps = 0.f;
                bf16x4 pq;
                #pragma unroll
                for (int ni = 0; ni < 4; ++ni) {
                    float pv = EXP2(sa[mi][ni][r]);
                    if (diag && (jt * 64 + ni * 16 + l15) > (qt * 128 + rowb + r)) pv = 0.f;
                    ps += pv;
                    pq[ni] = (bf16)pv;
                }
                *(bf16x4*)&p_w[(mi * 16 + quad * 4 + r) * 72 + l15 * 4] = pq;
                l_r[mi][r] += ps;
            }
        }

        // ---- O += P V ----
        #pragma unroll
        for (int kk = 0; kk < 2; ++kk) {
            bf16x8 pa[2];
            #pragma unroll
            for (int mi = 0; mi < 2; ++mi)
                pa[mi] = *(const bf16x8*)&p_w[(mi * 16 + l15) * 72 + kk * 32 + quad * 8];
            #pragma unroll
            for (int di = 0; di < 8; ++di) {
                bf16x8 vb = *(const bf16x8*)&v_lds[(kk * 4 + quad) * 1024 + (di * 16 + l15) * 8];
                #pragma unroll
                for (int mi = 0; mi < 2; ++mi)
                    Of[mi][di] = __builtin_amdgcn_mfma_f32_16x16x32_bf16(pa[mi], vb, Of[mi][di], 0, 0, 0);
            }
        }
    }

    // ---- final partial ----
    {
        const size_t slotq = ((size_t)bh * 16 + pqt) * SPLIT + s0;
        #pragma unroll
        for (int mi = 0; mi < 2; ++mi)
            #pragma unroll
            for (int r = 0; r < 4; ++r) {
                float ls = l_r[mi][r];
                ls += __shfl_xor(ls, 1); ls += __shfl_xor(ls, 2);
                ls += __shfl_xor(ls, 4); ls += __shfl_xor(ls, 8);
                const int row = w * 32 + mi * 16 + quad * 4 + r;
                if (l15 == 0) Pl[slotq * 128 + row] = ls;
                bf16* pr = PO + (slotq * 128 + row) * 128;
                #pragma unroll
                for (int di = 0; di < 8; ++di)
                    pr[di * 16 + l15] = (bf16)Of[mi][di][r];
            }
    }
}

// ---- combine: O = sum(PO)/sum(Pl), store [B,T,H,D] ----
__device__ __forceinline__ void combine_body(
    int idx, const bf16* PO, const float* Pl, bf16* Ob)
{
    const int dcol = (idx & 15) * 8;
    const int rowg = idx >> 4;
    const int bh = rowg >> 11, qrow = rowg & 2047;
    const int qt = qrow >> 7, row = qrow & 127;
    const int ns = (2 * qt + 2 < SPLIT) ? (2 * qt + 2) : SPLIT;

    float acc[8] = {};
    float l = 0.f;
    for (int s = 0; s < ns; ++s) {
        const size_t base = (((size_t)bh * 16 + qt) * SPLIT + s) * 128 + row;
        bf16x8 po = *(const bf16x8*)&PO[base * 128 + dcol];
        #pragma unroll
        for (int jj = 0; jj < 8; ++jj) acc[jj] += (float)po[jj];
        l += Pl[base];
    }
    const float inv = 1.f / l;
    const int b = bh >> 3, hh = bh & 7, t = qt * 128 + row;
    bf16x8 o;
    #pragma unroll
    for (int jj = 0; jj < 8; ++jj) o[jj] = (bf16)(acc[jj] * inv);
    *(bf16x8*)(Ob + ((size_t)(b * T_SEQ + t) * NH + hh) * HD + dcol) = o;
}

// ---- out_proj: 128x64 tiles, BK=64 swizzled, r8 dbuf pipeline.
// smem: a[2][8192] | b[2][4096] (48 KB). ----
__device__ __forceinline__ void out_proj_body(
    int bx, int tid, bf16* smem,
    const bf16* Ob, const bf16* Wot, float* out)
{
    bf16* a_lds = smem;            // [2][8192]
    bf16* b_lds = smem + 16384;    // [2][4096]

    const int nt = bx & 15, mt = bx >> 4;
    const int n0 = nt * 64, m0 = mt * 128;

    const int lane = tid & 63, w = tid >> 6;
    const int quad = lane >> 4, l15 = lane & 15;
    const int wr = w >> 1, wc = w & 1;
    const int srow = lane >> 3;

    const int csw = ((lane & 7) ^ srow) * 8;
    const bf16* gA = Ob  + (size_t)m0 * MDL + csw;
    const bf16* gB = Wot + (size_t)n0 * MDL + csw;

    f32x4 acc[4][2] = {};

    auto stage = [&](int k0, int buf) {
        #pragma unroll
        for (int i = 0; i < 4; ++i) {
            const int ch = w * 4 + i;
            const int row = ch * 8 + srow;
            __builtin_amdgcn_global_load_lds(GLB(gA + (size_t)row * MDL + k0),
                                             LDS(&a_lds[buf * 8192 + ch * 512]), 16, 0, 0);
        }
        #pragma unroll
        for (int i = 0; i < 2; ++i) {
            const int ch = w * 2 + i;
            const int row = ch * 8 + srow;
            __builtin_amdgcn_global_load_lds(GLB(gB + (size_t)row * MDL + k0),
                                             LDS(&b_lds[buf * 4096 + ch * 512]), 16, 0, 0);
        }
    };

    auto compute = [&](int buf) {
        #pragma unroll
        for (int hh = 0; hh < 2; ++hh) {
            bf16x8 af[4], bfr[2];
            #pragma unroll
            for (int mi = 0; mi < 4; ++mi) {
                const int ra = wr * 64 + mi * 16 + l15;
                af[mi] = *(const bf16x8*)&a_lds[buf * 8192 + ra * 64 + ((hh * 4 + quad) ^ (ra & 7)) * 8];
            }
            #pragma unroll
            for (int ni = 0; ni < 2; ++ni) {
                const int rb = wc * 32 + ni * 16 + l15;
                bfr[ni] = *(const bf16x8*)&b_lds[buf * 4096 + rb * 64 + ((hh * 4 + quad) ^ (rb & 7)) * 8];
            }
            #pragma unroll
            for (int mi = 0; mi < 4; ++mi)
                #pragma unroll
                for (int ni = 0; ni < 2; ++ni)
                    acc[mi][ni] = __builtin_amdgcn_mfma_f32_16x16x32_bf16(af[mi], bfr[ni], acc[mi][ni], 0, 0, 0);
        }
    };

    __syncthreads();                   // smem reuse guard (prev phase)
    stage(0, 0);
    __syncthreads();

    #pragma unroll 1
    for (int k0 = 0; k0 < MDL; k0 += 128) {
        stage(k0 + 64, 1);
        compute(0);
        __syncthreads();
        if (k0 + 128 < MDL) stage(k0 + 128, 0);
        compute(1);
        __syncthreads();
    }

    #pragma unroll
    for (int mi = 0; mi < 4; ++mi)
        #pragma unroll
        for (int r = 0; r < 4; ++r) {
            int row_g = m0 + wr * 64 + mi * 16 + quad * 4 + r;
            float* crow = out + (size_t)row_g * MDL + n0;
            #pragma unroll
            for (int ni = 0; ni < 2; ++ni)
                crow[wc * 32 + ni * 16 + l15] = acc[mi][ni][r];
        }
}

// ===========================================================================
// Cooperative mega-kernel: all 5 phases, 4 grid syncs, grid 512x256 =
// exactly 2 blocks/CU co-resident (LDS 64KB, launch_bounds(256,2) caps
// VGPR<=256 -> 8 waves/CU — the residency every phase already ran at).
// Removes 4 kernel-launch boundaries (~10µs each per the missing-time
// accounting: 121µs of kernel time vs 190.8µs e2e).
// ===========================================================================
__global__ __launch_bounds__(256, 2) void mega_kernel(
    const float* __restrict__ x,  const float* __restrict__ wq,
    const float* __restrict__ wk, const float* __restrict__ wv,
    const float* __restrict__ wo,
    bf16* xb, bf16* Wt, bf16* Wot,
    bf16* Qb, bf16* Kt, bf16* Vt,
    bf16* PO, float* Pl, bf16* Ob, float* out)
{
    __shared__ bf16 smem[32768];   // 64 KB, reused by every phase
    const int tid = threadIdx.x, bid = blockIdx.x;
    cg::grid_group grid = cg::this_grid();

    #pragma unroll 1
    for (int vb = bid; vb < 3072; vb += 512)
        prep_body(vb, tid, smem, x, wq, wk, wv, wo, xb, Wt, Wot);
    grid.sync();

    #pragma unroll 1
    for (int vb = bid; vb < 768; vb += 512)
        qkv_body(vb, tid, smem, xb, Wt, Qb, Kt, Vt);
    grid.sync();

    attn_body(bid, tid, smem, Qb, Kt, Vt, PO, Pl);
    grid.sync();

    #pragma unroll 1
    for (int vb = bid; vb < 2048; vb += 512)
        combine_body(vb * 256 + tid, PO, Pl, Ob);
    grid.sync();

    out_proj_body(bid, tid, smem, Ob, Wot, out);
}

// ===========================================================================
// Fallback standalone kernels (identical bodies) if cooperative launch is
// unavailable — this is exactly the r8 five-kernel configuration.
// ===========================================================================
__global__ __launch_bounds__(256) void prep_kernel(
    const float* __restrict__ x, const float* __restrict__ wq,
    const float* __restrict__ wk, const float* __restrict__ wv,
    const float* __restrict__ wo,
    bf16* __restrict__ xb, bf16* __restrict__ Wt, bf16* __restrict__ Wot)
{
    __shared__ bf16 t_lds[64 * 72];
    prep_body(blockIdx.x, threadIdx.x, t_lds, x, wq, wk, wv, wo, xb, Wt, Wot);
}

__global__ __launch_bounds__(256) void qkv_rope_kernel(
    const bf16* __restrict__ xb, const bf16* __restrict__ Wt,
    bf16* __restrict__ Qb, bf16* __restrict__ Kt, bf16* __restrict__ Vt)
{
    __shared__ bf16 smem[32768];
    qkv_body(blockIdx.x, threadIdx.x, smem, xb, Wt, Qb, Kt, Vt);
}

__global__ __launch_bounds__(256) void attn_kernel(
    const bf16* __restrict__ Qb, const bf16* __restrict__ Kt,
    const bf16* __restrict__ Vt, bf16* __restrict__ PO, float* __restrict__ Pl)
{
    __shared__ bf16 smem[8192 + 8192 + 4 * 32 * 72];
    attn_body(blockIdx.x, threadIdx.x, smem, Qb, Kt, Vt, PO, Pl);
}

__global__ __launch_bounds__(256) void attn_combine_kernel(
    const bf16* __restrict__ PO, const float* __restrict__ Pl,
    bf16* __restrict__ Ob)
{
    combine_body(blockIdx.x * 256 + threadIdx.x, PO, Pl, Ob);
}

__global__ __launch_bounds__(256) void out_proj_kernel(
    const bf16* __restrict__ Ob, const bf16* __restrict__ Wot,
    float* __restrict__ out)
{
    __shared__ bf16 smem[16384 + 8192];
    out_proj_body(blockIdx.x, threadIdx.x, smem, Ob, Wot, out);
}

// ---------------------------------------------------------------------------
extern "C" void kernel_launch(void* const* d_in, const int* in_sizes, int n_in,
                              void* d_out, int out_size, void* d_ws, size_t ws_size,
                              hipStream_t stream) {
    const float* x  = (const float*)d_in[0];
    const float* wq = (const float*)d_in[1];
    const float* wk = (const float*)d_in[2];
    const float* wv = (const float*)d_in[3];
    const float* wo = (const float*)d_in[4];
    float* out = (float*)d_out;

    const size_t NTOK = (size_t)2 * NH * T_SEQ * HD;  // 4,194,304 elems
    bf16*  Qb  = (bf16*)d_ws;
    bf16*  Kt  = Qb + NTOK;
    bf16*  Vt  = Kt + NTOK;
    bf16*  Ob  = Vt + NTOK;
    bf16*  Wot = Ob + NTOK;                           // 1 M elems
    bf16*  PO  = Wot + (size_t)MDL * MDL;             // 16*16*SPLIT*128*128
    float* Pl  = (float*)(PO + (size_t)16 * 16 * SPLIT * 128 * 128);

    // xb / Wt scratch live inside d_out (16 MB) — dead before out_proj writes.
    bf16* xbuf = (bf16*)d_out;
    bf16* Wt   = xbuf + (size_t)4096 * MDL;

    int dev = 0;
    (void)hipGetDevice(&dev);
    int coop = 0;
    (void)hipDeviceGetAttribute(&coop, hipDeviceAttributeCooperativeLaunch, dev);

    hipError_t e = hipErrorUnknown;
    if (coop) {
        void* args[] = {
            (void*)&x, (void*)&wq, (void*)&wk, (void*)&wv, (void*)&wo,
            (void*)&xbuf, (void*)&Wt, (void*)&Wot,
            (void*)&Qb, (void*)&Kt, (void*)&Vt,
            (void*)&PO, (void*)&Pl, (void*)&Ob, (void*)&out };
        e = hipLaunchCooperativeKernel((const void*)mega_kernel,
                                       dim3(512), dim3(256), args, 0, stream);
    }
    if (e != hipSuccess) {
        (void)hipGetLastError();          // clear, fall back to 5-kernel path
        prep_kernel<<<3072, 256, 0, stream>>>(x, wq, wk, wv, wo, xbuf, Wt, Wot);
        qkv_rope_kernel<<<768, 256, 0, stream>>>(xbuf, Wt, Qb, Kt, Vt);
        attn_kernel<<<16 * 8 * SPLIT, 256, 0, stream>>>(Qb, Kt, Vt, PO, Pl);
        attn_combine_kernel<<<2048, 256, 0, stream>>>(PO, Pl, Ob);
        out_proj_kernel<<<512, 256, 0, stream>>>(Ob, Wot, out);
    }
}

// Round 11
// 179.688 us; speedup vs baseline: 2.5191x; 2.5191x over previous
//
#include <hip/hip_runtime.h>
#include <hip/hip_cooperative_groups.h>

namespace cg = cooperative_groups;

#define T_SEQ 2048
#define MDL   1024
#define NH    8
#define HD    128
#define SPLIT 4

typedef __bf16 bf16;
typedef __bf16 bf16x8 __attribute__((ext_vector_type(8)));
typedef __bf16 bf16x4 __attribute__((ext_vector_type(4)));
typedef float  f32x4  __attribute__((ext_vector_type(4)));

#define GLB(p) ((const __attribute__((address_space(1))) void*)(p))
#define LDS(p) ((__attribute__((address_space(3))) void*)(p))

#if __has_builtin(__builtin_amdgcn_exp2f)
#define EXP2(x) __builtin_amdgcn_exp2f(x)
#else
#define EXP2(x) __expf((x) * 0.6931471805599453f)
#endif

// Q is pre-scaled by 2^-7 * log2(e) so attention P = exp2(QK) directly.
#define QSCALE 0.011271055f

// K image per (bh, jt<32): [d>>3][t&63][d&7]          (8192 elems)
// V image per (bh, jt<32): [p>>3][d][p&7], p = 4*(t&15) + (t>>4)  (j-permuted)

// ===========================================================================
// Phase bodies (shared between the cooperative mega-kernel and the 5-kernel
// fallback). All LDS passed as a pointer into one 64 KB block.
// ===========================================================================

// ---- prep: vb<2048: x fp32->bf16; vb>=2048: weight transpose to B^T ----
__device__ __forceinline__ void prep_body(
    int vb, int tid, bf16* t_lds,
    const float* x, const float* wq, const float* wk, const float* wv,
    const float* wo, bf16* xb, bf16* Wt, bf16* Wot)
{
    if (vb < 2048) {
        size_t i = ((size_t)vb * 256 + tid) * 8;
        float4 v0 = *(const float4*)(x + i);
        float4 v1 = *(const float4*)(x + i + 4);
        bf16x8 o;
        o[0]=(bf16)v0.x; o[1]=(bf16)v0.y; o[2]=(bf16)v0.z; o[3]=(bf16)v0.w;
        o[4]=(bf16)v1.x; o[5]=(bf16)v1.y; o[6]=(bf16)v1.z; o[7]=(bf16)v1.w;
        *(bf16x8*)(xb + i) = o;
        return;
    }
    const int bx = vb - 2048;
    const int sec = bx >> 8;
    const int tile = bx & 255;
    const int k0 = (tile >> 4) * 64, n0 = (tile & 15) * 64;
    const float* src = sec == 0 ? wq : sec == 1 ? wk : sec == 2 ? wv : wo;
    bf16* dst = sec < 3 ? (Wt + (size_t)sec * MDL * MDL) : Wot;

    const int ir = tid >> 2, jc = (tid & 3) * 16;
    const float* sp = src + (size_t)(k0 + ir) * MDL + n0 + jc;
    __syncthreads();                    // t_lds WAR guard across vb iterations
    #pragma unroll
    for (int c = 0; c < 4; ++c) {
        float4 v = *(const float4*)(sp + c * 4);
        bf16x4 o; o[0]=(bf16)v.x; o[1]=(bf16)v.y; o[2]=(bf16)v.z; o[3]=(bf16)v.w;
        *(bf16x4*)&t_lds[ir * 72 + jc + c * 4] = o;
    }
    __syncthreads();
    bf16x8 o0, o1;
    #pragma unroll
    for (int jj = 0; jj < 8; ++jj) {
        o0[jj] = t_lds[(jc + jj) * 72 + ir];
        o1[jj] = t_lds[(jc + 8 + jj) * 72 + ir];
    }
    bf16* dp = dst + (size_t)(n0 + ir) * MDL + k0 + jc;
    *(bf16x8*)dp = o0;
    *(bf16x8*)(dp + 8) = o1;
}

// ---- qkv GEMM + RoPE: BK=64, swizzled reads (r7), single-barrier
// double-buffered pipeline (r8). smem = 64 KB: a[2][8192] | b[2][8192].
// 92 VGPR standalone — fits the 128-VGPR mega cap. ----
__device__ __forceinline__ void qkv_body(
    int bx, int tid, bf16* smem,
    const bf16* xb, const bf16* Wt,
    bf16* Qb, bf16* Kt, bf16* Vt)
{
    bf16* a_lds = smem;
    bf16* b_lds = smem + 16384;

    const int nt = bx % 24, mt = bx / 24;
    const int n0 = nt * 128, m0 = mt * 128;
    const int section = n0 >> 10;
    const int h = (n0 & 1023) >> 7;

    const int lane = tid & 63, w = tid >> 6;
    const int quad = lane >> 4, l15 = lane & 15;
    const int wr = w >> 1, wc = w & 1;
    const int srow = lane >> 3;

    const int csw = ((lane & 7) ^ srow) * 8;   // inverse-swizzled source col
    const bf16* gA = xb + (size_t)m0 * MDL + csw;
    const bf16* gB = Wt + (size_t)n0 * MDL + csw;

    f32x4 acc[4][4] = {};

    auto stage = [&](int k0, int buf) {
        #pragma unroll
        for (int i = 0; i < 4; ++i) {
            const int ch = w * 4 + i;
            const int row = ch * 8 + srow;
            __builtin_amdgcn_global_load_lds(GLB(gA + (size_t)row * MDL + k0),
                                             LDS(&a_lds[buf * 8192 + ch * 512]), 16, 0, 0);
            __builtin_amdgcn_global_load_lds(GLB(gB + (size_t)row * MDL + k0),
                                             LDS(&b_lds[buf * 8192 + ch * 512]), 16, 0, 0);
        }
    };

    auto compute = [&](int buf) {
        #pragma unroll
        for (int hh = 0; hh < 2; ++hh) {
            bf16x8 af[4], bfr[4];
            #pragma unroll
            for (int mi = 0; mi < 4; ++mi) {
                const int ra = wr * 64 + mi * 16 + l15;
                af[mi] = *(const bf16x8*)&a_lds[buf * 8192 + ra * 64 + ((hh * 4 + quad) ^ (ra & 7)) * 8];
            }
            #pragma unroll
            for (int ni = 0; ni < 4; ++ni) {
                const int rb = wc * 64 + ni * 16 + l15;
                bfr[ni] = *(const bf16x8*)&b_lds[buf * 8192 + rb * 64 + ((hh * 4 + quad) ^ (rb & 7)) * 8];
            }
            #pragma unroll
            for (int mi = 0; mi < 4; ++mi)
                #pragma unroll
                for (int ni = 0; ni < 4; ++ni)
                    acc[mi][ni] = __builtin_amdgcn_mfma_f32_16x16x32_bf16(af[mi], bfr[ni], acc[mi][ni], 0, 0, 0);
        }
    };

    __syncthreads();                       // smem reuse guard (prev vb/phase)
    stage(0, 0);
    __syncthreads();                       // buf0 ready

    #pragma unroll 1
    for (int k0 = 0; k0 < MDL; k0 += 128) {
        stage(k0 + 64, 1);                 // prefetch flies under compute(0)
        compute(0);
        __syncthreads();                   // drains prefetch; buf1 ready
        if (k0 + 128 < MDL) stage(k0 + 128, 0);
        compute(1);
        __syncthreads();
    }

    const int bdx = m0 >> 11;
    const int t0 = m0 & (T_SEQ - 1);
    const int bh = bdx * NH + h;

    if (section == 2) {
        // ---- V -> j-permuted image via LDS, linear coalesced out ----
        #pragma unroll
        for (int c = 0; c < 2; ++c) {
            if (wc == c) {
                #pragma unroll
                for (int mi = 0; mi < 4; ++mi)
                    #pragma unroll
                    for (int r = 0; r < 4; ++r) {
                        int p = 16 * quad + 4 * r + mi;       // permuted pos
                        int base = (wr * 8 + (p >> 3)) * 512 + (p & 7);
                        #pragma unroll
                        for (int ni = 0; ni < 4; ++ni)
                            smem[base + (ni * 16 + l15) * 8] = (bf16)acc[mi][ni][r];
                    }
            }
            __syncthreads();
            {
                const int t8 = tid >> 4;
                bf16* vp = Vt + ((size_t)(bh * 32 + (t0 >> 6) + (t8 >> 3))) * 8192
                              + (t8 & 7) * 1024 + c * 512 + (tid & 15) * 32;
                #pragma unroll
                for (int k = 0; k < 4; ++k)
                    *(bf16x8*)(vp + k * 8) = *(const bf16x8*)&smem[tid * 32 + k * 8];
            }
            __syncthreads();
        }
        return;
    }

    float fr_n[2];
    #pragma unroll
    for (int ni = 0; ni < 2; ++ni)
        fr_n[ni] = __expf(-(float)(ni * 16 + l15) * 0.28782313662425573f);

    if (section == 0) {
        // ---- Q: [bh][t][d], RoPE on d<64, all scaled by QSCALE ----
        #pragma unroll
        for (int mi = 0; mi < 4; ++mi) {
            #pragma unroll
            for (int r = 0; r < 4; ++r) {
                int t = t0 + wr * 64 + mi * 16 + quad * 4 + r;
                bf16* orow = Qb + ((size_t)bh * T_SEQ + t) * HD;
                if (wc == 0) {
                    #pragma unroll
                    for (int ni = 0; ni < 2; ++ni) {
                        int d = ni * 16 + l15;
                        float ang = (float)t * fr_n[ni];
                        float sn = __sinf(ang), cs = __cosf(ang);
                        float ev = acc[mi][ni][r];
                        float ov = acc[mi][ni + 2][r];
                        orow[d]      = (bf16)((ev * cs - ov * sn) * QSCALE);
                        orow[d + 32] = (bf16)((ev * sn + ov * cs) * QSCALE);
                    }
                } else {
                    #pragma unroll
                    for (int ni = 0; ni < 4; ++ni)
                        orow[64 + ni * 16 + l15] = (bf16)(acc[mi][ni][r] * QSCALE);
                }
            }
        }
    } else {
        // ---- K -> image via LDS (half = one 64-t jt tile), RoPE fused ----
        #pragma unroll
        for (int c = 0; c < 2; ++c) {
            if (wr == c) {
                #pragma unroll
                for (int mi = 0; mi < 4; ++mi) {
                    #pragma unroll
                    for (int r = 0; r < 4; ++r) {
                        int tl = mi * 16 + quad * 4 + r;
                        int t = t0 + c * 64 + tl;
                        if (wc == 0) {
                            #pragma unroll
                            for (int ni = 0; ni < 2; ++ni) {
                                int d = ni * 16 + l15;
                                float ang = (float)t * fr_n[ni];
                                float sn = __sinf(ang), cs = __cosf(ang);
                                float ev = acc[mi][ni][r];
                                float ov = acc[mi][ni + 2][r];
                                smem[(d >> 3) * 512 + tl * 8 + (d & 7)] = (bf16)(ev * cs - ov * sn);
                                int d2 = d + 32;
                                smem[(d2 >> 3) * 512 + tl * 8 + (d2 & 7)] = (bf16)(ev * sn + ov * cs);
                            }
                        } else {
                            #pragma unroll
                            for (int ni = 0; ni < 4; ++ni) {
                                int d = 64 + ni * 16 + l15;
                                smem[(d >> 3) * 512 + tl * 8 + (d & 7)] = (bf16)acc[mi][ni][r];
                            }
                        }
                    }
                }
            }
            __syncthreads();
            {
                bf16* kp = Kt + ((size_t)(bh * 32 + (t0 >> 6) + c)) * 8192 + tid * 32;
                #pragma unroll
                for (int k = 0; k < 4; ++k)
                    *(bf16x8*)(kp + k * 8) = *(const bf16x8*)&smem[tid * 32 + k * 8];
            }
            __syncthreads();
        }
    }
}

// ---- attn: r4 DMA-STAGING variant — fits 128 VGPR (measured r4: VGPR=128,
// no spill signature). Chosen for the mega kernel because r9's reg-prefetch
// body (140 VGPR) spilled under the (256,2) cap (+100MB scratch traffic,
// 371µs). global_load_lds replaces the 32-VGPR kreg/vreg staging buffer;
// SP=4, XCD remap (2 heads/XCD = 4MB L2-resident KV, r3: FETCH 35->12.4MB).
// smem: k[8192] | v[8192] | p[4][2304]. ----
__device__ __forceinline__ void attn_body(
    int bx, int tid, bf16* smem,
    const bf16* Qb, const bf16* Kt, const bf16* Vt,
    bf16* PO, float* Pl)
{
    bf16* k_lds = smem;
    bf16* v_lds = smem + 8192;
    const int lane = tid & 63, w = tid >> 6;
    bf16* p_w = smem + 16384 + w * (32 * 72);

    const int quad = lane >> 4, l15 = lane & 15;
    const int xcd  = bx & 7;
    const int slot = bx >> 3;
    const int bh   = xcd * 2 + (slot >> 5);
    const int s0   = slot & (SPLIT - 1);
    const int ip   = (slot >> 2) & 7;
    const int tA = 2 * ip + 2;

    const bf16* Kbh = Kt + (size_t)bh * 32 * 8192;
    const bf16* Vbh = Vt + (size_t)bh * 32 * 8192;

    bf16x8 qf[2][4];
    f32x4 Of[2][8];
    float l_r[2][4];

    // Direct DMA staging: LDS dest = wave-uniform base (chunk*4KB + w*1KB)
    // + lane*16B; global src is per-lane (tid*16B into the tile image).
    auto stage = [&](int g) {
        const int jt = (g < tA) ? g : g - tA;
        const bf16* kt = Kbh + (size_t)jt * 8192 + tid * 8;
        const bf16* vt = Vbh + (size_t)jt * 8192 + tid * 8;
        #pragma unroll
        for (int k = 0; k < 4; ++k) {
            __builtin_amdgcn_global_load_lds(GLB(kt + k * 2048),
                                             LDS(&k_lds[k * 2048 + w * 512]), 16, 0, 0);
            __builtin_amdgcn_global_load_lds(GLB(vt + k * 2048),
                                             LDS(&v_lds[k * 2048 + w * 512]), 16, 0, 0);
        }
    };

    int pqt = -1;

    #pragma unroll 1
    for (int g = s0; g < 34; g += SPLIT) {
        const int ph = (g >= tA);
        const int qt = ph ? 15 - ip : ip;
        const int jt = ph ? g - tA : g;

        if (qt != pqt) {
            if (pqt >= 0) {
                const size_t slotq = ((size_t)bh * 16 + pqt) * SPLIT + s0;
                #pragma unroll
                for (int mi = 0; mi < 2; ++mi)
                    #pragma unroll
                    for (int r = 0; r < 4; ++r) {
                        float ls = l_r[mi][r];
                        ls += __shfl_xor(ls, 1); ls += __shfl_xor(ls, 2);
                        ls += __shfl_xor(ls, 4); ls += __shfl_xor(ls, 8);
                        const int row = w * 32 + mi * 16 + quad * 4 + r;
                        if (l15 == 0) Pl[slotq * 128 + row] = ls;
                        bf16* pr = PO + (slotq * 128 + row) * 128;
                        #pragma unroll
                        for (int di = 0; di < 8; ++di)
                            pr[di * 16 + l15] = (bf16)Of[mi][di][r];
                    }
            }
            #pragma unroll
            for (int mi = 0; mi < 2; ++mi) {
                const bf16* qrow = Qb + ((size_t)bh * T_SEQ + qt * 128 + w * 32 + mi * 16 + l15) * HD + quad * 8;
                #pragma unroll
                for (int kk = 0; kk < 4; ++kk)
                    qf[mi][kk] = *(const bf16x8*)(qrow + kk * 32);
                #pragma unroll
                for (int di = 0; di < 8; ++di) Of[mi][di] = (f32x4){0.f, 0.f, 0.f, 0.f};
                #pragma unroll
                for (int r = 0; r < 4; ++r) l_r[mi][r] = 0.f;
            }
            pqt = qt;
        }

        __syncthreads();          // all waves done reading prev tile
        stage(g);                 // DMA this tile straight into LDS
        __syncthreads();          // vmcnt(0) drain -> tiles visible

        // ---- S = Q K^T ----
        f32x4 sa[2][4] = {};
        #pragma unroll
        for (int kk = 0; kk < 4; ++kk) {
            bf16x8 kb[4];
            #pragma unroll
            for (int ni = 0; ni < 4; ++ni)
                kb[ni] = *(const bf16x8*)&k_lds[(kk * 4 + quad) * 512 + (ni * 16 + l15) * 8];
            #pragma unroll
            for (int ni = 0; ni < 4; ++ni)
                #pragma unroll
                for (int mi = 0; mi < 2; ++mi)
                    sa[mi][ni] = __builtin_amdgcn_mfma_f32_16x16x32_bf16(qf[mi][kk], kb[ni], sa[mi][ni], 0, 0, 0);
        }

        // ---- P = exp2(S), mask on diagonal tiles ----
        const bool diag = (jt >= 2 * qt);
        #pragma unroll
        for (int mi = 0; mi < 2; ++mi) {
            const int rowb = w * 32 + mi * 16 + quad * 4;
            #pragma unroll
            for (int r = 0; r < 4; ++r) {
                float ps = 0.f;
                bf16x4 pq;
                #pragma unroll
                for (int ni = 0; ni < 4; ++ni) {
                    float pv = EXP2(sa[mi][ni][r]);
                    if (diag && (jt * 64 + ni * 16 + l15) > (qt * 128 + rowb + r)) pv = 0.f;
                    ps += pv;
                    pq[ni] = (bf16)pv;
                }
                *(bf16x4*)&p_w[(mi * 16 + quad * 4 + r) * 72 + l15 * 4] = pq;
                l_r[mi][r] += ps;
            }
        }

        // ---- O += P V ----
        #pragma unroll
        for (int kk = 0; kk < 2; ++kk) {
            bf16x8 pa[2];
            #pragma unroll
            for (int mi = 0; mi < 2; ++mi)
                pa[mi] = *(const bf16x8*)&p_w[(mi * 16 + l15) * 72 + kk * 32 + quad * 8];
            #pragma unroll
            for (int di = 0; di < 8; ++di) {
                bf16x8 vb = *(const bf16x8*)&v_lds[(kk * 4 + quad) * 1024 + (di * 16 + l15) * 8];
                #pragma unroll
                for (int mi = 0; mi < 2; ++mi)
                    Of[mi][di] = __builtin_amdgcn_mfma_f32_16x16x32_bf16(pa[mi], vb, Of[mi][di], 0, 0, 0);
            }
        }
    }

    // ---- final partial ----
    {
        const size_t slotq = ((size_t)bh * 16 + pqt) * SPLIT + s0;
        #pragma unroll
        for (int mi = 0; mi < 2; ++mi)
            #pragma unroll
            for (int r = 0; r < 4; ++r) {
                float ls = l_r[mi][r];
                ls += __shfl_xor(ls, 1); ls += __shfl_xor(ls, 2);
                ls += __shfl_xor(ls, 4); ls += __shfl_xor(ls, 8);
                const int row = w * 32 + mi * 16 + quad * 4 + r;
                if (l15 == 0) Pl[slotq * 128 + row] = ls;
                bf16* pr = PO + (slotq * 128 + row) * 128;
                #pragma unroll
                for (int di = 0; di < 8; ++di)
                    pr[di * 16 + l15] = (bf16)Of[mi][di][r];
            }
    }
}

// ---- combine: O = sum(PO)/sum(Pl), store [B,T,H,D] ----
__device__ __forceinline__ void combine_body(
    int idx, const bf16* PO, const float* Pl, bf16* Ob)
{
    const int dcol = (idx & 15) * 8;
    const int rowg = idx >> 4;
    const int bh = rowg >> 11, qrow = rowg & 2047;
    const int qt = qrow >> 7, row = qrow & 127;
    const int ns = (2 * qt + 2 < SPLIT) ? (2 * qt + 2) : SPLIT;

    float acc[8] = {};
    float l = 0.f;
    for (int s = 0; s < ns; ++s) {
        const size_t base = (((size_t)bh * 16 + qt) * SPLIT + s) * 128 + row;
        bf16x8 po = *(const bf16x8*)&PO[base * 128 + dcol];
        #pragma unroll
        for (int jj = 0; jj < 8; ++jj) acc[jj] += (float)po[jj];
        l += Pl[base];
    }
    const float inv = 1.f / l;
    const int b = bh >> 3, hh = bh & 7, t = qt * 128 + row;
    bf16x8 o;
    #pragma unroll
    for (int jj = 0; jj < 8; ++jj) o[jj] = (bf16)(acc[jj] * inv);
    *(bf16x8*)(Ob + ((size_t)(b * T_SEQ + t) * NH + hh) * HD + dcol) = o;
}

// ---- out_proj: 128x64 tiles, BK=64 swizzled, r8 dbuf pipeline.
// smem: a[2][8192] | b[2][4096] (48 KB). ----
__device__ __forceinline__ void out_proj_body(
    int bx, int tid, bf16* smem,
    const bf16* Ob, const bf16* Wot, float* out)
{
    bf16* a_lds = smem;            // [2][8192]
    bf16* b_lds = smem + 16384;    // [2][4096]

    const int nt = bx & 15, mt = bx >> 4;
    const int n0 = nt * 64, m0 = mt * 128;

    const int lane = tid & 63, w = tid >> 6;
    const int quad = lane >> 4, l15 = lane & 15;
    const int wr = w >> 1, wc = w & 1;
    const int srow = lane >> 3;

    const int csw = ((lane & 7) ^ srow) * 8;
    const bf16* gA = Ob  + (size_t)m0 * MDL + csw;
    const bf16* gB = Wot + (size_t)n0 * MDL + csw;

    f32x4 acc[4][2] = {};

    auto stage = [&](int k0, int buf) {
        #pragma unroll
        for (int i = 0; i < 4; ++i) {
            const int ch = w * 4 + i;
            const int row = ch * 8 + srow;
            __builtin_amdgcn_global_load_lds(GLB(gA + (size_t)row * MDL + k0),
                                             LDS(&a_lds[buf * 8192 + ch * 512]), 16, 0, 0);
        }
        #pragma unroll
        for (int i = 0; i < 2; ++i) {
            const int ch = w * 2 + i;
            const int row = ch * 8 + srow;
            __builtin_amdgcn_global_load_lds(GLB(gB + (size_t)row * MDL + k0),
                                             LDS(&b_lds[buf * 4096 + ch * 512]), 16, 0, 0);
        }
    };

    auto compute = [&](int buf) {
        #pragma unroll
        for (int hh = 0; hh < 2; ++hh) {
            bf16x8 af[4], bfr[2];
            #pragma unroll
            for (int mi = 0; mi < 4; ++mi) {
                const int ra = wr * 64 + mi * 16 + l15;
                af[mi] = *(const bf16x8*)&a_lds[buf * 8192 + ra * 64 + ((hh * 4 + quad) ^ (ra & 7)) * 8];
            }
            #pragma unroll
            for (int ni = 0; ni < 2; ++ni) {
                const int rb = wc * 32 + ni * 16 + l15;
                bfr[ni] = *(const bf16x8*)&b_lds[buf * 4096 + rb * 64 + ((hh * 4 + quad) ^ (rb & 7)) * 8];
            }
            #pragma unroll
            for (int mi = 0; mi < 4; ++mi)
                #pragma unroll
                for (int ni = 0; ni < 2; ++ni)
                    acc[mi][ni] = __builtin_amdgcn_mfma_f32_16x16x32_bf16(af[mi], bfr[ni], acc[mi][ni], 0, 0, 0);
        }
    };

    __syncthreads();                   // smem reuse guard (prev phase)
    stage(0, 0);
    __syncthreads();

    #pragma unroll 1
    for (int k0 = 0; k0 < MDL; k0 += 128) {
        stage(k0 + 64, 1);
        compute(0);
        __syncthreads();
        if (k0 + 128 < MDL) stage(k0 + 128, 0);
        compute(1);
        __syncthreads();
    }

    #pragma unroll
    for (int mi = 0; mi < 4; ++mi)
        #pragma unroll
        for (int r = 0; r < 4; ++r) {
            int row_g = m0 + wr * 64 + mi * 16 + quad * 4 + r;
            float* crow = out + (size_t)row_g * MDL + n0;
            #pragma unroll
            for (int ni = 0; ni < 2; ++ni)
                crow[wc * 32 + ni * 16 + l15] = acc[mi][ni][r];
        }
}

// ===========================================================================
// Cooperative mega-kernel: all 5 phases, 4 grid syncs, grid 512x256.
// Launch config = r9's PROVEN envelope __launch_bounds__(256,2) (captured,
// replayed, completed). r9's defect was the attn body: reg-prefetch needs
// 140 VGPR > the 128 cap -> spills (+100MB scratch, 371µs). Fixed by using
// the r4 DMA-staging attn body (fits 128, measured). r10's uncapped variant
// risked >256 VGPR -> 1 block/CU -> cooperative validation fails AT GRAPH
// REPLAY (capture records success) -> harness exception with no fallback.
// ===========================================================================
__global__ __launch_bounds__(256, 2) void mega_kernel(
    const float* __restrict__ x,  const float* __restrict__ wq,
    const float* __restrict__ wk, const float* __restrict__ wv,
    const float* __restrict__ wo,
    bf16* xb, bf16* Wt, bf16* Wot,
    bf16* Qb, bf16* Kt, bf16* Vt,
    bf16* PO, float* Pl, bf16* Ob, float* out)
{
    __shared__ bf16 smem[32768];   // 64 KB, reused by every phase
    const int tid = threadIdx.x, bid = blockIdx.x;
    cg::grid_group grid = cg::this_grid();

    #pragma unroll 1
    for (int vb = bid; vb < 3072; vb += 512)
        prep_body(vb, tid, smem, x, wq, wk, wv, wo, xb, Wt, Wot);
    grid.sync();

    #pragma unroll 1
    for (int vb = bid; vb < 768; vb += 512)
        qkv_body(vb, tid, smem, xb, Wt, Qb, Kt, Vt);
    grid.sync();

    attn_body(bid, tid, smem, Qb, Kt, Vt, PO, Pl);
    grid.sync();

    #pragma unroll 1
    for (int vb = bid; vb < 2048; vb += 512)
        combine_body(vb * 256 + tid, PO, Pl, Ob);
    grid.sync();

    out_proj_body(bid, tid, smem, Ob, Wot, out);
}

// ===========================================================================
// Fallback standalone kernels — the r8 five-kernel configuration (190.8µs
// known-good) if cooperative launch is unavailable or under-resident.
// ===========================================================================
__global__ __launch_bounds__(256) void prep_kernel(
    const float* __restrict__ x, const float* __restrict__ wq,
    const float* __restrict__ wk, const float* __restrict__ wv,
    const float* __restrict__ wo,
    bf16* __restrict__ xb, bf16* __restrict__ Wt, bf16* __restrict__ Wot)
{
    __shared__ bf16 t_lds[64 * 72];
    prep_body(blockIdx.x, threadIdx.x, t_lds, x, wq, wk, wv, wo, xb, Wt, Wot);
}

__global__ __launch_bounds__(256) void qkv_rope_kernel(
    const bf16* __restrict__ xb, const bf16* __restrict__ Wt,
    bf16* __restrict__ Qb, bf16* __restrict__ Kt, bf16* __restrict__ Vt)
{
    __shared__ bf16 smem[32768];
    qkv_body(blockIdx.x, threadIdx.x, smem, xb, Wt, Qb, Kt, Vt);
}

__global__ __launch_bounds__(256) void attn_kernel(
    const bf16* __restrict__ Qb, const bf16* __restrict__ Kt,
    const bf16* __restrict__ Vt, bf16* __restrict__ PO, float* __restrict__ Pl)
{
    __shared__ bf16 smem[8192 + 8192 + 4 * 32 * 72];
    attn_body(blockIdx.x, threadIdx.x, smem, Qb, Kt, Vt, PO, Pl);
}

__global__ __launch_bounds__(256) void attn_combine_kernel(
    const bf16* __restrict__ PO, const float* __restrict__ Pl,
    bf16* __restrict__ Ob)
{
    combine_body(blockIdx.x * 256 + threadIdx.x, PO, Pl, Ob);
}

__global__ __launch_bounds__(256) void out_proj_kernel(
    const bf16* __restrict__ Ob, const bf16* __restrict__ Wot,
    float* __restrict__ out)
{
    __shared__ bf16 smem[16384 + 8192];
    out_proj_body(blockIdx.x, threadIdx.x, smem, Ob, Wot, out);
}

// ---------------------------------------------------------------------------
extern "C" void kernel_launch(void* const* d_in, const int* in_sizes, int n_in,
                              void* d_out, int out_size, void* d_ws, size_t ws_size,
                              hipStream_t stream) {
    const float* x  = (const float*)d_in[0];
    const float* wq = (const float*)d_in[1];
    const float* wk = (const float*)d_in[2];
    const float* wv = (const float*)d_in[3];
    const float* wo = (const float*)d_in[4];
    float* out = (float*)d_out;

    const size_t NTOK = (size_t)2 * NH * T_SEQ * HD;  // 4,194,304 elems
    bf16*  Qb  = (bf16*)d_ws;
    bf16*  Kt  = Qb + NTOK;
    bf16*  Vt  = Kt + NTOK;
    bf16*  Ob  = Vt + NTOK;
    bf16*  Wot = Ob + NTOK;                           // 1 M elems
    bf16*  PO  = Wot + (size_t)MDL * MDL;             // 16*16*SPLIT*128*128
    float* Pl  = (float*)(PO + (size_t)16 * 16 * SPLIT * 128 * 128);

    // xb / Wt scratch live inside d_out (16 MB) — dead before out_proj writes.
    bf16* xbuf = (bf16*)d_out;
    bf16* Wt   = xbuf + (size_t)4096 * MDL;

    int dev = 0;
    (void)hipGetDevice(&dev);
    int coop = 0;
    (void)hipDeviceGetAttribute(&coop, hipDeviceAttributeCooperativeLaunch, dev);

    // Residency guard: cooperative needs all 512 blocks co-resident.
    // Query the ACTUAL occupancy of mega_kernel (2 blocks/CU x 256 CU = 512)
    // so a regalloc surprise can never produce a replay-time launch failure.
    int maxBlk = 0;
    if (coop)
        (void)hipOccupancyMaxActiveBlocksPerMultiprocessor(
            &maxBlk, (const void*)mega_kernel, 256, 0);

    hipError_t e = hipErrorUnknown;
    if (coop && maxBlk >= 2) {
        void* args[] = {
            (void*)&x, (void*)&wq, (void*)&wk, (void*)&wv, (void*)&wo,
            (void*)&xbuf, (void*)&Wt, (void*)&Wot,
            (void*)&Qb, (void*)&Kt, (void*)&Vt,
            (void*)&PO, (void*)&Pl, (void*)&Ob, (void*)&out };
        e = hipLaunchCooperativeKernel((const void*)mega_kernel,
                                       dim3(512), dim3(256), args, 0, stream);
    }
    if (e != hipSuccess) {
        (void)hipGetLastError();          // clear, fall back to 5-kernel path
        prep_kernel<<<3072, 256, 0, stream>>>(x, wq, wk, wv, wo, xbuf, Wt, Wot);
        qkv_rope_kernel<<<768, 256, 0, stream>>>(xbuf, Wt, Qb, Kt, Vt);
        attn_kernel<<<16 * 8 * SPLIT, 256, 0, stream>>>(Qb, Kt, Vt, PO, Pl);
        attn_combine_kernel<<<2048, 256, 0, stream>>>(PO, Pl, Ob);
        out_proj_kernel<<<512, 256, 0, stream>>>(Ob, Wot, out);
    }
}